// Round 8
// baseline (261.945 us; speedup 1.0000x reference)
//
#include <hip/hip_runtime.h>
#include <hip/hip_bf16.h>

#define NN  4
#define CIN 96
#define C1  128
#define C2  144
#define HH  128
#define WW  256

typedef short bf16x8 __attribute__((ext_vector_type(8)));
typedef float f32x4  __attribute__((ext_vector_type(4)));
typedef unsigned int u32x4 __attribute__((ext_vector_type(4)));

__device__ __forceinline__ short f2bs(float v) {
    __hip_bfloat16 b = __float2bfloat16(v);
    short s; __builtin_memcpy(&s, &b, 2); return s;
}

// ---------------------------------------------------------------------------
// NCHW fp32 -> NHWC bf16 transpose of feat. Block = (n,h).
__global__ __launch_bounds__(256) void transpose_feat(
    const float* __restrict__ feat, short* __restrict__ featT)
{
    __shared__ unsigned int lds[48 * 258];        // 49.5 KB
    const int tid = threadIdx.x;
    const int h = blockIdx.x & (HH - 1);
    const int n = blockIdx.x >> 7;

    #pragma unroll 4
    for (int cp = 0; cp < 48; ++cp) {
        float v0 = feat[(((size_t)n * CIN + 2 * cp    ) * HH + h) * WW + tid];
        float v1 = feat[(((size_t)n * CIN + 2 * cp + 1) * HH + h) * WW + tid];
        unsigned int p = (unsigned int)(unsigned short)f2bs(v0)
                       | ((unsigned int)(unsigned short)f2bs(v1) << 16);
        lds[cp * 258 + tid] = p;
    }
    __syncthreads();
    const size_t pbase = ((size_t)(n * HH + h) * WW + tid) * CIN;
    #pragma unroll
    for (int rec = 0; rec < 12; ++rec) {
        u32x4 v;
        #pragma unroll
        for (int k = 0; k < 4; ++k) v[k] = lds[(rec * 4 + k) * 258 + tid];
        *(u32x4*)&featT[pbase + rec * 8] = v;
    }
}

// ---------------------------------------------------------------------------
// Pack weights (co,ci,3,3) fp32 -> B-frag order bf16:
// wp[(((kci*9+tap)*nct + ct)*64 + lane)*8 + j], co=ct*16+col, ci=kci*32+quad*8+j
__global__ __launch_bounds__(256) void pack_wB(
    const float* __restrict__ w, short* __restrict__ wp,
    int cin, int nct, int total)
{
    int i = blockIdx.x * 256 + threadIdx.x;
    if (i >= total) return;
    const int j    = i & 7;
    const int col  = (i >> 3) & 15;
    const int quad = (i >> 7) & 3;
    int t = i >> 9;
    const int ct  = t % nct;  t /= nct;
    const int tap = t % 9;
    const int kci = t / 9;
    const int co = ct * 16 + col;
    const int ci = kci * 32 + quad * 8 + j;
    wp[i] = f2bs(w[((size_t)co * cin + ci) * 9 + tap]);
}

// ---------------------------------------------------------------------------
// conv1: featT NHWC -> hfeat NHWC. Block = (n,h,whalf): 256 thr / 4 waves =
// 2 ct-groups x 2 px-halves; wave = 4 ct x 4 mt. Window 3x130 px in LDS
// (stride 36), register-prefetched staging.
__global__ __launch_bounds__(256, 3) void conv1_mfma(
    const short* __restrict__ featT, const short* __restrict__ w1p,
    const float* __restrict__ b1, short* __restrict__ hfeat)
{
    __shared__ short lds[3 * 130 * 36];           // 28,080 B
    const int tid  = threadIdx.x;
    const int wb   = blockIdx.x & 1;
    const int h    = (blockIdx.x >> 1) & (HH - 1);
    const int n    = blockIdx.x >> 8;
    const int lane = tid & 63, wave = tid >> 6;
    const int quad = lane >> 4, col = lane & 15;
    const int cg = wave >> 1;                     // ct-group: ct = cg*4+j
    const int ms = wave & 1;                      // m-half:  mt = ms*4+i

    f32x4 acc[4][4] = {};                         // [mt i][ct j]
    bf16x8 pf[7];

    // stage-unit decode: idx in [0,1560) -> (row, px, cig)
    auto ldu = [&](int kci, int idx) -> bf16x8 {
        const int row = idx / 520;
        const int rem = idx - row * 520;
        const int px = rem >> 2, cig = rem & 3;
        const int hh = h + row - 1, gw = wb * 128 + px - 1;
        bf16x8 v = {};
        if (hh >= 0 && hh < HH && gw >= 0 && gw < WW)
            v = *(const bf16x8*)
                &featT[(((size_t)n * HH + hh) * WW + gw) * CIN + kci * 32 + cig * 8];
        return v;
    };

    #pragma unroll
    for (int u = 0; u < 6; ++u) pf[u] = ldu(0, u * 256 + tid);
    if (tid < 24) pf[6] = ldu(0, 1536 + tid);

    for (int kci = 0; kci < 3; ++kci) {
        if (kci) __syncthreads();
        #pragma unroll
        for (int u = 0; u < 6; ++u) {
            const int idx = u * 256 + tid;
            const int row = idx / 520, rem = idx - row * 520;
            *(bf16x8*)&lds[(row * 130 + (rem >> 2)) * 36 + (rem & 3) * 8] = pf[u];
        }
        if (tid < 24) {
            const int idx = 1536 + tid;
            const int row = idx / 520, rem = idx - row * 520;
            *(bf16x8*)&lds[(row * 130 + (rem >> 2)) * 36 + (rem & 3) * 8] = pf[6];
        }
        if (kci < 2) {
            #pragma unroll
            for (int u = 0; u < 6; ++u) pf[u] = ldu(kci + 1, u * 256 + tid);
            if (tid < 24) pf[6] = ldu(kci + 1, 1536 + tid);
        }
        __syncthreads();

        #pragma unroll
        for (int tap = 0; tap < 9; ++tap) {
            const int dh = tap / 3, dw = tap % 3;
            bf16x8 af[4];
            #pragma unroll
            for (int i = 0; i < 4; ++i)
                af[i] = *(const bf16x8*)
                    &lds[(dh * 130 + (ms * 4 + i) * 16 + col + dw) * 36 + quad * 8];
            const short* bp = w1p + (((size_t)((kci * 9 + tap) * 8 + cg * 4)) << 9)
                            + (lane << 3);
            #pragma unroll
            for (int j = 0; j < 4; ++j) {
                const bf16x8 bfr = *(const bf16x8*)(bp + ((size_t)j << 9));
                #pragma unroll
                for (int i = 0; i < 4; ++i)
                    acc[i][j] = __builtin_amdgcn_mfma_f32_16x16x32_bf16(
                        af[i], bfr, acc[i][j], 0, 0, 0);
            }
        }
    }

    float bias[4];
    #pragma unroll
    for (int j = 0; j < 4; ++j) bias[j] = b1[(cg * 4 + j) * 16 + col];
    #pragma unroll
    for (int i = 0; i < 4; ++i)
        #pragma unroll
        for (int r = 0; r < 4; ++r) {
            const int w = wb * 128 + (ms * 4 + i) * 16 + quad * 4 + r;
            const size_t ro = ((size_t)(n * HH + h) * WW + w) * C1;
            #pragma unroll
            for (int j = 0; j < 4; ++j) {
                float a = acc[i][j][r] + bias[j];
                a = a > 0.f ? a : 0.1f * a;       // LeakyReLU(0.1)
                hfeat[ro + (cg * 4 + j) * 16 + col] = f2bs(a);
            }
        }
}

// ---------------------------------------------------------------------------
// conv2 + fused softmax/upsample. Block = (n,h): 768 thr / 12 waves =
// 3 ct-groups x 4 px-quarters. Window 3x258 (stride 36) + flow row in LDS.
// Epilogue: 4 px-quarter passes exchanging logits through (dead) window LDS.
__global__ __launch_bounds__(768, 2) void conv2_fused(
    const short* __restrict__ hfeat, const short* __restrict__ w2p,
    const float* __restrict__ b2, const float* __restrict__ flow,
    float* __restrict__ out)
{
    __shared__ short lds[3 * 258 * 36];           // 55,728 B (window / logits)
    __shared__ float flowL[2][3][258];            // 6,192 B
    const int tid  = threadIdx.x;
    const int h    = blockIdx.x & (HH - 1);
    const int n    = blockIdx.x >> 7;
    const int lane = tid & 63, wave = tid >> 6;
    const int quad = lane >> 4, col = lane & 15;
    const int cg = wave >> 2;                     // 0..2: k = cg*3+j
    const int ms = wave & 3;                      // 0..3: mt = ms*4+i

    f32x4 acc[4][3] = {};                         // [mt i][ct j]
    bf16x8 pf[5];

    // stage flow row-window (used only in epilogue; K-loop barriers cover it)
    for (int s = tid; s < 1548; s += 768) {
        const int c = s / 774;
        const int rem = s - c * 774;
        const int row = rem / 258, px = rem - row * 258;
        const int hh = h + row - 1, gw = px - 1;
        float v = 0.f;
        if (hh >= 0 && hh < HH && gw >= 0 && gw < WW)
            v = flow[((size_t)(n * 2 + c) * HH + hh) * WW + gw];
        flowL[c][row][px] = v;
    }

    auto ldu = [&](int kci, int idx) -> bf16x8 {
        const int row = idx / 1032;
        const int rem = idx - row * 1032;
        const int px = rem >> 2, cig = rem & 3;
        const int hh = h + row - 1, gw = px - 1;
        bf16x8 v = {};
        if (hh >= 0 && hh < HH && gw >= 0 && gw < WW)
            v = *(const bf16x8*)
                &hfeat[(((size_t)n * HH + hh) * WW + gw) * C1 + kci * 32 + cig * 8];
        return v;
    };

    #pragma unroll
    for (int u = 0; u < 4; ++u) pf[u] = ldu(0, u * 768 + tid);
    if (tid < 24) pf[4] = ldu(0, 3072 + tid);

    for (int kci = 0; kci < 4; ++kci) {
        if (kci) __syncthreads();
        #pragma unroll
        for (int u = 0; u < 4; ++u) {
            const int idx = u * 768 + tid;
            const int row = idx / 1032, rem = idx - row * 1032;
            *(bf16x8*)&lds[(row * 258 + (rem >> 2)) * 36 + (rem & 3) * 8] = pf[u];
        }
        if (tid < 24) {
            const int idx = 3072 + tid;
            const int row = idx / 1032, rem = idx - row * 1032;
            *(bf16x8*)&lds[(row * 258 + (rem >> 2)) * 36 + (rem & 3) * 8] = pf[4];
        }
        if (kci < 3) {
            #pragma unroll
            for (int u = 0; u < 4; ++u) pf[u] = ldu(kci + 1, u * 768 + tid);
            if (tid < 24) pf[4] = ldu(kci + 1, 3072 + tid);
        }
        __syncthreads();

        #pragma unroll
        for (int tap = 0; tap < 9; ++tap) {
            const int dh = tap / 3, dw = tap % 3;
            bf16x8 af[4];
            #pragma unroll
            for (int i = 0; i < 4; ++i)
                af[i] = *(const bf16x8*)
                    &lds[(dh * 258 + (ms * 4 + i) * 16 + col + dw) * 36 + quad * 8];
            const short* bp = w2p + (((size_t)((kci * 9 + tap) * 9 + cg * 3)) << 9)
                            + (lane << 3);
            #pragma unroll
            for (int j = 0; j < 3; ++j) {
                const bf16x8 bfr = *(const bf16x8*)(bp + ((size_t)j << 9));
                #pragma unroll
                for (int i = 0; i < 4; ++i)
                    acc[i][j] = __builtin_amdgcn_mfma_f32_16x16x32_bf16(
                        af[i], bfr, acc[i][j], 0, 0, 0);
            }
        }
    }

    // ---- epilogue: 4 px-quarter passes through LDS ----
    float bias3[3];
    #pragma unroll
    for (int j = 0; j < 3; ++j) bias3[j] = b2[(cg * 3 + j) * 16 + col];
    float* lfl = (float*)lds;                     // logits [64 px][148]
    const int H4 = 4 * HH, W4 = 4 * WW;

    for (int msp = 0; msp < 4; ++msp) {
        __syncthreads();                          // prior reads of lds done
        if (ms == msp) {
            #pragma unroll
            for (int i = 0; i < 4; ++i)
                #pragma unroll
                for (int j = 0; j < 3; ++j)
                    #pragma unroll
                    for (int r = 0; r < 4; ++r) {
                        const int pxl = i * 16 + quad * 4 + r;
                        lfl[pxl * 148 + (cg * 3 + j) * 16 + col] =
                            acc[i][j][r] + bias3[j];
                    }
        }
        __syncthreads();
        for (int c = tid; c < 1024; c += 768) {
            const int pxl = c >> 4, ab = c & 15;
            const int w = msp * 64 + pxl;
            float v[9], mx = -1e30f;
            #pragma unroll
            for (int k = 0; k < 9; ++k) {
                v[k] = 0.25f * lfl[pxl * 148 + k * 16 + ab];
                mx = fmaxf(mx, v[k]);
            }
            float s = 0.f;
            #pragma unroll
            for (int k = 0; k < 9; ++k) { v[k] = __expf(v[k] - mx); s += v[k]; }
            const float inv = 4.f / s;            // folds the 4*flow scale
            float o0 = 0.f, o1 = 0.f;
            #pragma unroll
            for (int ki = 0; ki < 3; ++ki)
                #pragma unroll
                for (int kj = 0; kj < 3; ++kj) {
                    const float wgt = v[ki * 3 + kj];
                    o0 += wgt * flowL[0][ki][w + kj];
                    o1 += wgt * flowL[1][ki][w + kj];
                }
            const int a = ab >> 2, b = ab & 3;
            const size_t o = ((size_t)(n * 2) * H4 + 4 * h + a) * W4 + 4 * w + b;
            out[o] = o0 * inv;
            out[o + (size_t)H4 * W4] = o1 * inv;
        }
    }
}

// ---------------------------------------------------------------------------
extern "C" void kernel_launch(void* const* d_in, const int* in_sizes, int n_in,
                              void* d_out, int out_size, void* d_ws, size_t ws_size,
                              hipStream_t stream)
{
    const float* flow = (const float*)d_in[0];
    const float* feat = (const float*)d_in[1];
    const float* w1   = (const float*)d_in[2];
    const float* b1   = (const float*)d_in[3];
    const float* w2   = (const float*)d_in[4];
    const float* b2   = (const float*)d_in[5];
    float* out = (float*)d_out;

    short* featT = (short*)d_ws;
    short* hfeat = featT + (size_t)NN * HH * WW * CIN;   // 12,582,912
    short* w1p   = hfeat + (size_t)NN * HH * WW * C1;    // 16,777,216
    short* w2p   = w1p + (size_t)3 * 9 * 8 * 512;        // 110,592

    const int tot1 = 3 * 9 * 8 * 512;                    // 110,592
    const int tot2 = 4 * 9 * 9 * 512;                    // 165,888

    transpose_feat<<<NN * HH, 256, 0, stream>>>(feat, featT);
    pack_wB<<<(tot1 + 255) / 256, 256, 0, stream>>>(w1, w1p, CIN, 8, tot1);
    pack_wB<<<(tot2 + 255) / 256, 256, 0, stream>>>(w2, w2p, C1, 9, tot2);
    conv1_mfma<<<NN * HH * 2, 256, 0, stream>>>(featT, w1p, b1, hfeat);
    conv2_fused<<<NN * HH, 768, 0, stream>>>(hfeat, w2p, b2, flow, out);
}

// Round 9
// 247.628 us; speedup vs baseline: 1.0578x; 1.0578x over previous
//
#include <hip/hip_runtime.h>
#include <hip/hip_bf16.h>

#define NN  4
#define CIN 96
#define C1  128
#define C2  144
#define HH  128
#define WW  256

typedef short bf16x8 __attribute__((ext_vector_type(8)));
typedef float f32x4  __attribute__((ext_vector_type(4)));
typedef unsigned int u32x4 __attribute__((ext_vector_type(4)));

// per-wave window: 3 rows x 66 px x (32ci = 8sh x 4), px stride 36 shorts
#define WSTRIDE 36
#define WROW    (66 * WSTRIDE)
#define WSIZE   (3 * WROW)          // 7128 shorts = 14,256 B per wave

__device__ __forceinline__ short f2bs(float v) {
    __hip_bfloat16 b = __float2bfloat16(v);
    short s; __builtin_memcpy(&s, &b, 2); return s;
}

// ---------------------------------------------------------------------------
// NCHW fp32 -> NHWC bf16 transpose of feat. Block = (n,h).
__global__ __launch_bounds__(256) void transpose_feat(
    const float* __restrict__ feat, short* __restrict__ featT)
{
    __shared__ unsigned int lds[48 * 258];        // 49.5 KB
    const int tid = threadIdx.x;
    const int h = blockIdx.x & (HH - 1);
    const int n = blockIdx.x >> 7;

    #pragma unroll 4
    for (int cp = 0; cp < 48; ++cp) {
        float v0 = feat[(((size_t)n * CIN + 2 * cp    ) * HH + h) * WW + tid];
        float v1 = feat[(((size_t)n * CIN + 2 * cp + 1) * HH + h) * WW + tid];
        unsigned int p = (unsigned int)(unsigned short)f2bs(v0)
                       | ((unsigned int)(unsigned short)f2bs(v1) << 16);
        lds[cp * 258 + tid] = p;
    }
    __syncthreads();
    const size_t pbase = ((size_t)(n * HH + h) * WW + tid) * CIN;
    #pragma unroll
    for (int rec = 0; rec < 12; ++rec) {
        u32x4 v;
        #pragma unroll
        for (int k = 0; k < 4; ++k) v[k] = lds[(rec * 4 + k) * 258 + tid];
        *(u32x4*)&featT[pbase + rec * 8] = v;
    }
}

// ---------------------------------------------------------------------------
// Pack weights (co,ci,3,3) fp32 -> B-frag order bf16:
// wp[(((kci*9+tap)*nct + ct)*64 + lane)*8 + j], co=ct*16+col, ci=kci*32+quad*8+j
__global__ __launch_bounds__(256) void pack_wB(
    const float* __restrict__ w, short* __restrict__ wp,
    int cin, int nct, int total)
{
    int i = blockIdx.x * 256 + threadIdx.x;
    if (i >= total) return;
    const int j    = i & 7;
    const int col  = (i >> 3) & 15;
    const int quad = (i >> 7) & 3;
    int t = i >> 9;
    const int ct  = t % nct;  t /= nct;
    const int tap = t % 9;
    const int kci = t / 9;
    const int co = ct * 16 + col;
    const int ci = kci * 32 + quad * 8 + j;
    wp[i] = f2bs(w[((size_t)co * cin + ci) * 9 + tap]);
}

// ---------------------------------------------------------------------------
// conv1: featT NHWC -> hfeat NHWC. NO BARRIERS: each wave stages its own
// 3x66-px window into private LDS (lgkmcnt-ordered), register-double-buffers
// the next chunk's staging loads, and free-runs. Block = (n,h,half), 4 waves:
// wave = (cg: 4 of 8 ct) x (ms: 64-px strip). XCD-swizzled blockIdx.
__global__ __launch_bounds__(256, 2) void conv1_mfma(
    const short* __restrict__ featT, const short* __restrict__ w1p,
    const float* __restrict__ b1, short* __restrict__ hfeat)
{
    __shared__ short lds[4 * WSIZE];              // 57,024 B
    const int tid  = threadIdx.x;
    const int b    = blockIdx.x;
    const int lid  = (b & 7) * 128 + (b >> 3);    // XCD h-band swizzle (1024)
    const int n    = lid >> 8;
    const int h    = (lid >> 1) & 127;
    const int half = lid & 1;
    const int lane = tid & 63, wave = tid >> 6;
    const int quad = lane >> 4, col = lane & 15;
    const int cg = wave >> 1, ms = wave & 1;
    const int w0 = half * 128 + ms * 64;
    short* wlds = lds + wave * WSIZE;

    f32x4 acc[4][4] = {};                         // [mt i][ct j]
    bf16x8 pf[13];

    auto ldu = [&](int kci, int u) -> bf16x8 {    // staging unit load
        const int idx = u * 64 + lane;
        bf16x8 v = {};
        if (idx < 792) {
            const int row = idx / 264;
            const int rem = idx - row * 264;
            const int px = rem >> 2, cig = rem & 3;
            const int hh = h + row - 1, gw = w0 + px - 1;
            if (hh >= 0 && hh < HH && gw >= 0 && gw < WW)
                v = *(const bf16x8*)
                    &featT[(((size_t)n * HH + hh) * WW + gw) * CIN + kci * 32 + cig * 8];
        }
        return v;
    };
    auto stu = [&](int u, bf16x8 v) {             // staging unit LDS write
        const int idx = u * 64 + lane;
        if (idx < 792) {
            const int row = idx / 264;
            const int rem = idx - row * 264;
            *(bf16x8*)&wlds[(row * 66 + (rem >> 2)) * WSTRIDE + (rem & 3) * 8] = v;
        }
    };

    #pragma unroll
    for (int u = 0; u < 13; ++u) pf[u] = ldu(0, u);

    for (int kci = 0; kci < 3; ++kci) {
        #pragma unroll
        for (int u = 0; u < 13; ++u) stu(u, pf[u]);
        if (kci < 2) {                            // prefetch next chunk; stays
            #pragma unroll                        // in flight through the taps
            for (int u = 0; u < 13; ++u) pf[u] = ldu(kci + 1, u);
        }
        #pragma unroll
        for (int tap = 0; tap < 9; ++tap) {
            const int dh = tap / 3, dw = tap % 3;
            bf16x8 af[4];
            #pragma unroll
            for (int i = 0; i < 4; ++i)
                af[i] = *(const bf16x8*)
                    &wlds[(dh * 66 + i * 16 + col + dw) * WSTRIDE + quad * 8];
            const short* bp = w1p + (((size_t)((kci * 9 + tap) * 8 + cg * 4)) << 9)
                            + (lane << 3);
            #pragma unroll
            for (int j = 0; j < 4; ++j) {
                const bf16x8 bfr = *(const bf16x8*)(bp + ((size_t)j << 9));
                #pragma unroll
                for (int i = 0; i < 4; ++i)
                    acc[i][j] = __builtin_amdgcn_mfma_f32_16x16x32_bf16(
                        af[i], bfr, acc[i][j], 0, 0, 0);
            }
        }
    }

    float bias[4];
    #pragma unroll
    for (int j = 0; j < 4; ++j) bias[j] = b1[(cg * 4 + j) * 16 + col];
    #pragma unroll
    for (int i = 0; i < 4; ++i)
        #pragma unroll
        for (int r = 0; r < 4; ++r) {
            const int w = w0 + i * 16 + quad * 4 + r;
            const size_t ro = ((size_t)(n * HH + h) * WW + w) * C1;
            #pragma unroll
            for (int j = 0; j < 4; ++j) {
                float a = acc[i][j][r] + bias[j];
                a = a > 0.f ? a : 0.1f * a;       // LeakyReLU(0.1)
                hfeat[ro + (cg * 4 + j) * 16 + col] = f2bs(a);
            }
        }
}

// ---------------------------------------------------------------------------
// conv2 + fused bias/0.25/softmax-9/convex-upsample. Same barrier-free
// per-wave structure; wave = 64-px strip x ALL 9 ct (acc 144) so the softmax
// runs entirely in registers (lane col = ab holds all 9 logits). Flow window
// staged into the dead LDS region post-K-loop (same wave, lgkmcnt-ordered).
__global__ __launch_bounds__(256, 2) void conv2_fused(
    const short* __restrict__ hfeat, const short* __restrict__ w2p,
    const float* __restrict__ b2, const float* __restrict__ flow,
    float* __restrict__ out)
{
    __shared__ short lds[4 * WSIZE];              // 57,024 B
    const int tid  = threadIdx.x;
    const int b    = blockIdx.x;
    const int lid  = (b & 7) * 64 + (b >> 3);     // XCD h-band swizzle (512)
    const int n    = lid >> 7;
    const int h    = lid & 127;
    const int lane = tid & 63, wave = tid >> 6;
    const int quad = lane >> 4, col = lane & 15;
    const int w0 = wave * 64;
    short* wlds = lds + wave * WSIZE;

    f32x4 acc[4][9] = {};                         // [mt i][ct k]

    auto ldu = [&](int kci, int u) -> bf16x8 {
        const int idx = u * 64 + lane;
        bf16x8 v = {};
        if (idx < 792) {
            const int row = idx / 264;
            const int rem = idx - row * 264;
            const int px = rem >> 2, cig = rem & 3;
            const int hh = h + row - 1, gw = w0 + px - 1;
            if (hh >= 0 && hh < HH && gw >= 0 && gw < WW)
                v = *(const bf16x8*)
                    &hfeat[(((size_t)n * HH + hh) * WW + gw) * C1 + kci * 32 + cig * 8];
        }
        return v;
    };

    for (int kci = 0; kci < 4; ++kci) {
        #pragma unroll
        for (int u = 0; u < 13; ++u) {
            const bf16x8 v = ldu(kci, u);
            const int idx = u * 64 + lane;
            if (idx < 792) {
                const int row = idx / 264;
                const int rem = idx - row * 264;
                *(bf16x8*)&wlds[(row * 66 + (rem >> 2)) * WSTRIDE + (rem & 3) * 8] = v;
            }
        }
        #pragma unroll
        for (int tap = 0; tap < 9; ++tap) {
            const int dh = tap / 3, dw = tap % 3;
            bf16x8 af[4];
            #pragma unroll
            for (int i = 0; i < 4; ++i)
                af[i] = *(const bf16x8*)
                    &wlds[(dh * 66 + i * 16 + col + dw) * WSTRIDE + quad * 8];
            const short* bp = w2p + (((size_t)((kci * 9 + tap) * 9)) << 9)
                            + (lane << 3);
            #pragma unroll
            for (int k = 0; k < 9; ++k) {
                const bf16x8 bfr = *(const bf16x8*)(bp + ((size_t)k << 9));
                #pragma unroll
                for (int i = 0; i < 4; ++i)
                    acc[i][k] = __builtin_amdgcn_mfma_f32_16x16x32_bf16(
                        af[i], bfr, acc[i][k], 0, 0, 0);
            }
        }
    }

    // ---- stage flow window into dead LDS (same wave -> no barrier) ----
    float* fl = (float*)wlds;                     // [ch*3+ki][66 px]
    #pragma unroll
    for (int u = 0; u < 7; ++u) {
        const int idx = u * 64 + lane;
        if (idx < 396) {
            const int ch = idx / 198;
            const int rem = idx - ch * 198;
            const int ki = rem / 66, px = rem - ki * 66;
            const int hh = h + ki - 1, gw = w0 + px - 1;
            float v = 0.f;
            if (hh >= 0 && hh < HH && gw >= 0 && gw < WW)
                v = flow[((size_t)(n * 2 + ch) * HH + hh) * WW + gw];
            fl[(ch * 3 + ki) * 66 + px] = v;
        }
    }

    // ---- register softmax + convex combination + 4x upsample ----
    float bias[9];
    #pragma unroll
    for (int k = 0; k < 9; ++k) bias[k] = b2[k * 16 + col];
    const int a_ = col >> 2, b_ = col & 3;
    const int H4 = 4 * HH, W4 = 4 * WW;

    #pragma unroll
    for (int i = 0; i < 4; ++i)
        #pragma unroll
        for (int r = 0; r < 4; ++r) {
            const int wl = i * 16 + quad * 4 + r;         // 0..63
            float v[9], mx = -1e30f;
            #pragma unroll
            for (int k = 0; k < 9; ++k) {
                v[k] = 0.25f * (acc[i][k][r] + bias[k]);
                mx = fmaxf(mx, v[k]);
            }
            float s = 0.f;
            #pragma unroll
            for (int k = 0; k < 9; ++k) { v[k] = __expf(v[k] - mx); s += v[k]; }
            const float inv = 4.f / s;                    // folds 4*flow
            float o0 = 0.f, o1 = 0.f;
            #pragma unroll
            for (int ki = 0; ki < 3; ++ki)
                #pragma unroll
                for (int kj = 0; kj < 3; ++kj) {
                    const float wgt = v[ki * 3 + kj];
                    o0 += wgt * fl[(0 * 3 + ki) * 66 + wl + kj];
                    o1 += wgt * fl[(1 * 3 + ki) * 66 + wl + kj];
                }
            const int w = w0 + wl;
            const size_t o = ((size_t)(n * 2) * H4 + 4 * h + a_) * W4 + 4 * w + b_;
            out[o] = o0 * inv;
            out[o + (size_t)H4 * W4] = o1 * inv;
        }
}

// ---------------------------------------------------------------------------
extern "C" void kernel_launch(void* const* d_in, const int* in_sizes, int n_in,
                              void* d_out, int out_size, void* d_ws, size_t ws_size,
                              hipStream_t stream)
{
    const float* flow = (const float*)d_in[0];
    const float* feat = (const float*)d_in[1];
    const float* w1   = (const float*)d_in[2];
    const float* b1   = (const float*)d_in[3];
    const float* w2   = (const float*)d_in[4];
    const float* b2   = (const float*)d_in[5];
    float* out = (float*)d_out;

    short* featT = (short*)d_ws;
    short* hfeat = featT + (size_t)NN * HH * WW * CIN;   // 12,582,912
    short* w1p   = hfeat + (size_t)NN * HH * WW * C1;    // 16,777,216
    short* w2p   = w1p + (size_t)3 * 9 * 8 * 512;        // 110,592

    const int tot1 = 3 * 9 * 8 * 512;                    // 110,592
    const int tot2 = 4 * 9 * 9 * 512;                    // 165,888

    transpose_feat<<<NN * HH, 256, 0, stream>>>(feat, featT);
    pack_wB<<<(tot1 + 255) / 256, 256, 0, stream>>>(w1, w1p, CIN, 8, tot1);
    pack_wB<<<(tot2 + 255) / 256, 256, 0, stream>>>(w2, w2p, C1, 9, tot2);
    conv1_mfma<<<NN * HH * 2, 256, 0, stream>>>(featT, w1p, b1, hfeat);
    conv2_fused<<<NN * HH, 256, 0, stream>>>(hfeat, w2p, b2, flow, out);
}